// Round 30
// baseline (633.200 us; speedup 1.0000x reference)
//
#include <hip/hip_runtime.h>
#include <hip/hip_bf16.h>
#include <math.h>

// Problem constants
#define NB 8
#define NIN 256
#define NHID 256
#define NMEM 64
#define NSEQ 2048
#define NFEAT 64
#define NOUTCH 320        // NFEAT + NHID
#define NFFT 4096
#define KBINS 2049        // NSEQ + 1

// ws layout (float offsets) — Z slot sized at RUNTIME from ws_size.
// order: FFTU | Z(och) | FHD | TW | HBUF ; f64 scratch & ubuf overlay Z.
#define FFTU_SZ (NB * NFEAT * KBINS * 2)               // 2,098,176 (8.4 MB)
#define FHD_SZ (NMEM * KBINS * 2)                      // 262,272 (1.05 MB)
#define TW_SZ (2048 * 2)                               // 16 KB
#define HBUF_SZ (NMEM * NSEQ)                          // 131,072 (0.52 MB)
#define FIXED_F (FFTU_SZ + FHD_SZ + TW_SZ + HBUF_SZ)   // 2,495,616 floats

// f64 scratch layout (doubles, based at Z slot; dead before ubuf is written)
#define DMM   0                      // 65x65 scaled blk
#define DTT0  4225                   // Taylor T ping
#define DTT1  8450                   // Taylor T pong
#define DEE0  12675                  // E ping
#define DEE1  16900                  // E pong
#define DPW   21125                  // pw[0..5] = Ad^(2^m), 6*4096
#define DWV   (DPW + 6 * 4096)       // W[r][j] = (Ad^r Bd)[j], 64x64
#define DMK2  (DWV + 4096)           // Mk[k] = (Ad^64)^k, 32*4096

// padded LDS index for FFT arrays (breaks power-of-2 stride bank conflicts)
#define FIDX(i) ((i) + ((i) >> 5) + ((i) >> 10))
#define FFT_LDS 4240
#define HF_LDS 2120

// ---------------------------------------------------------------------------
// shared 4096-pt radix-2 DIT core (data already bit-reversed into XR/XI)
// ---------------------------------------------------------------------------
__device__ __forceinline__ void fft4096_core(float* XR, float* XI,
                                             const float2* TWS, bool inverse) {
#pragma unroll 1
  for (int s = 1; s <= 12; ++s) {
    int half = 1 << (s - 1);
    int shift = 12 - s;
#pragma unroll
    for (int q = 0; q < 8; ++q) {
      int bf = threadIdx.x + q * 256;
      int j = bf & (half - 1);
      int base = ((bf >> (s - 1)) << s) + j;
      float2 w = TWS[j << shift];
      float wr = w.x, wi = inverse ? -w.y : w.y;
      int i0 = FIDX(base), i1 = FIDX(base + half);
      float ar = XR[i0], ai = XI[i0];
      float br = XR[i1], bi = XI[i1];
      float tr = wr * br - wi * bi, ti = wr * bi + wi * br;
      XR[i0] = ar + tr; XI[i0] = ai + ti;
      XR[i1] = ar - tr; XI[i1] = ai - ti;
    }
    __syncthreads();
  }
}

// 2048-pt core: same table, twiddle index j<<(12-s), s=1..11; 4 bf/thread.
__device__ __forceinline__ void fft2048_core(float* XR, float* XI,
                                             const float2* TWS, bool inverse) {
#pragma unroll 1
  for (int s = 1; s <= 11; ++s) {
    int half = 1 << (s - 1);
    int shift = 12 - s;
#pragma unroll
    for (int q = 0; q < 4; ++q) {
      int bf = threadIdx.x + q * 256;
      int j = bf & (half - 1);
      int base = ((bf >> (s - 1)) << s) + j;
      float2 w = TWS[j << shift];
      float wr = w.x, wi = inverse ? -w.y : w.y;
      int i0 = FIDX(base), i1 = FIDX(base + half);
      float ar = XR[i0], ai = XI[i0];
      float br = XR[i1], bi = XI[i1];
      float tr = wr * br - wi * bi, ti = wr * bi + wi * br;
      XR[i0] = ar + tr; XI[i0] = ai + ti;
      XR[i1] = ar - tr; XI[i1] = ai - ti;
    }
    __syncthreads();
  }
}

// ---------------------------------------------------------------------------
// k0: tw[m] = exp(-2*pi*i*m/4096), m in [0,2048), double precision.
// ---------------------------------------------------------------------------
__global__ void k0_tw(float2* __restrict__ tw) {
  int m = blockIdx.x * 256 + threadIdx.x;
  if (m < 2048) {
    double ang = -2.0 * 3.14159265358979323846 * (double)m / 4096.0;
    tw[m] = make_float2((float)cos(ang), (float)sin(ang));
  }
}

// ---------------------------------------------------------------------------
// kA chain: expm + power tables (Taylor 8 terms; s=2, scale=0.25 hardcoded).
// (launch-chain form: 17-block parallel matmuls)
// ---------------------------------------------------------------------------
__global__ __launch_bounds__(256) void kinit(double* __restrict__ D) {
  int e = blockIdx.x * 256 + threadIdx.x;
  if (e < 4225) {
    int i = e / 65, j = e % 65;
    double val = 0.0;
    if (i < 64) {
      double R = (2.0 * i + 1.0) / 2048.0;
      if (j < 64) val = R * ((i < j) ? -1.0 : (((i - j) & 1) ? 1.0 : -1.0));
      else        val = R * ((i & 1) ? -1.0 : 1.0);   // Bc = R*(-1)^i
    }
    D[DMM + e] = 0.25 * val;
    double id = (i == j) ? 1.0 : 0.0;
    D[DTT0 + e] = id; D[DEE0 + e] = id;
  }
}
__global__ __launch_bounds__(256) void kmm65(const double* __restrict__ A,
                                             const double* __restrict__ B,
                                             double* __restrict__ C,
                                             double* __restrict__ E, double kd) {
  int e = blockIdx.x * 256 + threadIdx.x;
  if (e >= 4225) return;
  int i = e / 65, j = e % 65;
  const double* ar = A + i * 65;
  double dot = 0.0;
  for (int l = 0; l < 65; ++l) dot += ar[l] * B[l * 65 + j];
  dot /= kd;
  C[e] = dot;
  if (E) E[e] += dot;
}
__global__ __launch_bounds__(256) void kext(const double* __restrict__ E,
                                            double* __restrict__ D) {
  int e = blockIdx.x * 256 + threadIdx.x;
  if (e < 4096) {
    int i = e >> 6, j = e & 63;
    D[DPW + e] = (double)(float)E[i * 65 + j];
    D[DMK2 + e] = (i == j) ? 1.0 : 0.0;
  } else if (e < 4160) {
    int j = e - 4096;
    D[DWV + j] = (double)(float)E[j * 65 + 64];
  }
}
__global__ __launch_bounds__(256) void kmm64(const double* __restrict__ A,
                                             const double* __restrict__ B,
                                             double* __restrict__ C) {
  int e = blockIdx.x * 256 + threadIdx.x;
  int i = e >> 6, j = e & 63;
  double dot = 0.0;
  for (int l = 0; l < 64; ++l) dot += A[i * 64 + l] * B[l * 64 + j];
  C[e] = dot;
}
__global__ __launch_bounds__(256) void kwlev(const double* __restrict__ P,
                                             double* __restrict__ W, int b0) {
  int tot = 64 * b0;
  for (int e = threadIdx.x; e < tot; e += 256) {
    int t = e >> 6, i = e & 63;
    double dot = 0.0;
    for (int l = 0; l < 64; ++l) dot += P[i * 64 + l] * W[t * 64 + l];
    W[(size_t)(b0 + t) * 64 + i] = dot;
  }
}
__global__ __launch_bounds__(256) void kmk(const double* __restrict__ Q,
                                           const double* __restrict__ Src,
                                           double* __restrict__ Out) {
  int t = blockIdx.y;
  int e = blockIdx.x * 256 + threadIdx.x;
  int i = e >> 6, j = e & 63;
  const double* B = Src + (size_t)t * 4096;
  double dot = 0.0;
  for (int l = 0; l < 64; ++l) dot += Q[i * 64 + l] * B[l * 64 + j];
  Out[(size_t)t * 4096 + e] = dot;
}

// ---------------------------------------------------------------------------
// kB: parallel impulse response. W transposed in LDS (round-17 conflict fix).
// ---------------------------------------------------------------------------
__global__ __launch_bounds__(256) void kB_cols(const double* __restrict__ D,
                                               float* __restrict__ H) {
  const double* W = D + DWV;
  const double* Mrow = D + DMK2 + (size_t)blockIdx.x * 4096;
  __shared__ double Ms[4096];
  __shared__ double WssT[4096];   // WssT[j*64 + r] = W[r*64 + j]
  const int tid = threadIdx.x;
  for (int e = tid; e < 4096; e += 256) {
    Ms[e] = Mrow[e];
    int r = e >> 6, j = e & 63;
    WssT[j * 64 + r] = W[e];
  }
  __syncthreads();
  const int c0 = blockIdx.x * 64;
  for (int e = tid; e < 4096; e += 256) {
    int i = e >> 6, r = e & 63;
    double dot = 0.0;
#pragma unroll 16
    for (int j = 0; j < 64; ++j) dot += Ms[i * 64 + j] * WssT[j * 64 + r];
    H[(size_t)i * NSEQ + c0 + r] = (float)dot;
  }
}

// ---------------------------------------------------------------------------
// kC: fHd[mi,k] = rfft(H[mi,:], n=4096)[k] via LDS FFT. 1 block/row.
// ---------------------------------------------------------------------------
__global__ __launch_bounds__(256) void kC_fft(const float* __restrict__ H,
                                              const float2* __restrict__ tw,
                                              float* __restrict__ fHd) {
  __shared__ float XR[FFT_LDS], XI[FFT_LDS];
  __shared__ float2 TWS[2048];
  const int tid = threadIdx.x;
  const int mi = blockIdx.x;
  const float* src = H + (size_t)mi * NSEQ;
  for (int i = tid; i < NFFT; i += 256) { XR[FIDX(i)] = 0.f; XI[FIDX(i)] = 0.f; }
  for (int i = tid; i < 2048; i += 256) TWS[i] = tw[i];
  __syncthreads();
  for (int i = tid; i < NSEQ; i += 256) {
    int r = __brev((unsigned)i) >> 20;
    XR[FIDX(r)] = src[i];
  }
  __syncthreads();
  fft4096_core(XR, XI, TWS, false);
  float2* dst = (float2*)fHd + (size_t)mi * KBINS;
  for (int k = tid; k < KBINS; k += 256)
    dst[k] = make_float2(XR[FIDX(k)], XI[FIDX(k)]);
}

// ---------------------------------------------------------------------------
// k1t: tiled GEMM out[b,o,s] = bias + sum_i Wu_w[o,i]*x[b,i,s]
// ---------------------------------------------------------------------------
__global__ __launch_bounds__(256) void k1t(
    const float* __restrict__ x, const float* __restrict__ Wuw,
    const float* __restrict__ Wub, const float* __restrict__ Whb,
    float* __restrict__ dout, float* __restrict__ ubuf) {
  __shared__ float xs[32][128];
  __shared__ float wsh[32][68];
  const int tid = threadIdx.x;
  const int b = blockIdx.z;
  const int o0 = blockIdx.y * 64;
  const int s0 = blockIdx.x * 128;
  const int sx = tid & 15, oy = tid >> 4;
  float acc[4][8];
#pragma unroll
  for (int j = 0; j < 4; ++j)
#pragma unroll
    for (int l = 0; l < 8; ++l) acc[j][l] = 0.f;

  for (int i0 = 0; i0 < 256; i0 += 32) {
#pragma unroll
    for (int e4 = tid; e4 < 1024; e4 += 256) {
      int ii = e4 >> 5, ss4 = (e4 & 31) << 2;
      float4 v = *(const float4*)&x[(size_t)(b * NIN + i0 + ii) * NSEQ + s0 + ss4];
      *(float4*)&xs[ii][ss4] = v;
    }
#pragma unroll
    for (int e4 = tid; e4 < 512; e4 += 256) {
      int oj = e4 >> 3, ii4 = (e4 & 7) << 2;
      float4 v = *(const float4*)&Wuw[(o0 + oj) * NIN + i0 + ii4];
      wsh[ii4][oj] = v.x; wsh[ii4 + 1][oj] = v.y;
      wsh[ii4 + 2][oj] = v.z; wsh[ii4 + 3][oj] = v.w;
    }
    __syncthreads();
#pragma unroll 8
    for (int kk = 0; kk < 32; ++kk) {
      float4 a = *(const float4*)&wsh[kk][oy * 4];
      float4 b0 = *(const float4*)&xs[kk][sx * 4];
      float4 b1 = *(const float4*)&xs[kk][64 + sx * 4];
      float av[4] = {a.x, a.y, a.z, a.w};
      float bv[8] = {b0.x, b0.y, b0.z, b0.w, b1.x, b1.y, b1.z, b1.w};
#pragma unroll
      for (int j = 0; j < 4; ++j)
#pragma unroll
        for (int l = 0; l < 8; ++l) acc[j][l] = fmaf(av[j], bv[l], acc[j][l]);
    }
    __syncthreads();
  }
#pragma unroll
  for (int j = 0; j < 4; ++j) {
    int o = o0 + oy * 4 + j;
    if (o < NHID) {
      float bias = Wub[o] + Whb[o];
      size_t base = ((size_t)b * NHID + o) * NSEQ + s0;
      float4 v0 = make_float4(acc[j][0] + bias, acc[j][1] + bias,
                              acc[j][2] + bias, acc[j][3] + bias);
      float4 v1 = make_float4(acc[j][4] + bias, acc[j][5] + bias,
                              acc[j][6] + bias, acc[j][7] + bias);
      *(float4*)&dout[base + sx * 4] = v0;
      *(float4*)&dout[base + 64 + sx * 4] = v1;
    } else {
      float bias = Wub[o];
      size_t base = ((size_t)b * NFEAT + (o - NHID)) * NSEQ + s0;
      float4 v0 = make_float4(fmaxf(acc[j][0] + bias, 0.f), fmaxf(acc[j][1] + bias, 0.f),
                              fmaxf(acc[j][2] + bias, 0.f), fmaxf(acc[j][3] + bias, 0.f));
      float4 v1 = make_float4(fmaxf(acc[j][4] + bias, 0.f), fmaxf(acc[j][5] + bias, 0.f),
                              fmaxf(acc[j][6] + bias, 0.f), fmaxf(acc[j][7] + bias, 0.f));
      *(float4*)&ubuf[base + sx * 4] = v0;
      *(float4*)&ubuf[base + 64 + sx * 4] = v1;
    }
  }
}

// ---------------------------------------------------------------------------
// k2h: HALF-SIZE forward rfft of u (round-24 proven).
// ---------------------------------------------------------------------------
__global__ __launch_bounds__(256) void k2h(
    const float* __restrict__ ubuf, const float2* __restrict__ tw,
    float* __restrict__ fftu) {
  __shared__ float XR[HF_LDS], XI[HF_LDS];
  __shared__ float2 TWS[2048];
  const int tid = threadIdx.x;
  const int b = blockIdx.x >> 6, f = blockIdx.x & 63;
  const float2* src2 = (const float2*)(ubuf + ((size_t)b * NFEAT + f) * NSEQ);
  for (int i = tid; i < 2048; i += 256) TWS[i] = tw[i];
  for (int n = tid; n < 2048; n += 256) {
    float2 y = (n < 1024) ? src2[n] : make_float2(0.f, 0.f);
    int r = __brev((unsigned)n) >> 21;   // 11-bit reversal
    XR[FIDX(r)] = y.x; XI[FIDX(r)] = y.y;
  }
  __syncthreads();
  fft2048_core(XR, XI, TWS, false);
  float2* dst = (float2*)fftu + ((size_t)b * NFEAT + f) * KBINS;
  for (int k = tid; k <= 2048; k += 256) {
    if (k < 2048) {
      int m = (2048 - k) & 2047;
      float yr = XR[FIDX(k)], yi = XI[FIDX(k)];
      float mr = XR[FIDX(m)], mi = XI[FIDX(m)];
      float ar = 0.5f * (yr + mr), ai = 0.5f * (yi - mi);
      float br = 0.5f * (yi + mi), bi = 0.5f * (mr - yr);
      float2 w = TWS[k];               // e^{-2pik/4096}
      float Xr = ar + w.x * br - w.y * bi;
      float Xi = ai + w.x * bi + w.y * br;
      dst[k] = make_float2(Xr, Xi);
    } else {
      dst[2048] = make_float2(XR[FIDX(0)] - XI[FIDX(0)], 0.f);
    }
  }
}

// ---------------------------------------------------------------------------
// k3m: fused G+Z, mi-outer register-G, two passes of 8 f's, fHc-free
// (round-22 k3g body, validated incl. post-timing) + runtime o-chunk merged
// grid (round-25). NEW COMBINATION: k3g's 33.8KB LDS / 112 VGPR allows
// 4 blocks/CU, which round-22's 640-block grid (2.06/CU supply) couldn't
// exploit — the merged 4224-block grid can. h read from global fHd
// (L2-resident, coalesced), same values/mi-order as fHc -> bit-identical.
// ---------------------------------------------------------------------------
#define WHT_STRIDE 132
#define K3_SMEM (64 * WHT_STRIDE)   // 8448 floats = 33.8 KB (= red size)
__global__ __launch_bounds__(256, 2) void k3m(
    const float* __restrict__ Whw, const float* __restrict__ fHd,
    const float* __restrict__ fftu, float* __restrict__ Zc,
    int ob0, int och, int nopair) {
  const int wgid = blockIdx.x;
  const int cxd = wgid & 7;
  const int sdx = wgid >> 3;
  const int opair = sdx % nopair;
  const int kt = cxd + 8 * (sdx / nopair);
  if (kt >= 33) return;

  __shared__ float smem[K3_SMEM];
  float* WhT = smem;                                   // [64][132]
  float (*red)[64][33] = (float(*)[64][33])smem;       // overlay, post-loop
  const int tid = threadIdx.x;
  const int ol0 = opair * 2;
  const int o0 = ob0 + ol0;
  const int k0 = kt * 64;

  for (int e4 = tid; e4 < 2048; e4 += 256) {
    int ol = e4 >> 10;
    int idx4 = e4 & 1023;
    int f = idx4 >> 4, mi4 = idx4 & 15;
    float4 v = *(const float4*)&Whw[(size_t)(o0 + ol) * 4096 + f * 64 + mi4 * 4];
    WhT[(mi4 * 4 + 0) * WHT_STRIDE + f * 2 + ol] = v.x;
    WhT[(mi4 * 4 + 1) * WHT_STRIDE + f * 2 + ol] = v.y;
    WhT[(mi4 * 4 + 2) * WHT_STRIDE + f * 2 + ol] = v.z;
    WhT[(mi4 * 4 + 3) * WHT_STRIDE + f * 2 + ol] = v.w;
  }
  __syncthreads();

  const int tk = tid & 63, g = tid >> 6;
  const int k = k0 + tk;
  const bool kok = (k < KBINS);
  const int kc = kok ? k : 2048;          // clamped (OOB-safe) bin index
  const float2* fu2 = (const float2*)fftu;
  const float2* fh2 = (const float2*)fHd;
  const size_t kb = (size_t)KBINS;

  float zr[2][8], zi[2][8];
#pragma unroll
  for (int ol = 0; ol < 2; ++ol)
#pragma unroll
    for (int b = 0; b < 8; ++b) { zr[ol][b] = 0.f; zi[ol][b] = 0.f; }

#pragma unroll 1
  for (int pass = 0; pass < 2; ++pass) {
    const int fbase = g * 16 + pass * 8;
    float2 ub[8], un[8];
#pragma unroll
    for (int b = 0; b < 8; ++b)
      ub[b] = kok ? fu2[((size_t)(b * NFEAT + fbase)) * kb + k]
                  : make_float2(0.f, 0.f);

    float G0r[8], G0i[8], G1r[8], G1i[8];
#pragma unroll
    for (int ff = 0; ff < 8; ++ff) { G0r[ff] = 0.f; G0i[ff] = 0.f;
                                     G1r[ff] = 0.f; G1i[ff] = 0.f; }

    float2 hb = fh2[kc];                   // mi = 0 (coalesced, L2-hit)
#pragma unroll 2
    for (int mi = 0; mi < 64; ++mi) {
      float2 hn = make_float2(0.f, 0.f);
      if (mi < 63) hn = fh2[(size_t)(mi + 1) * kb + kc];   // prefetch
      const float* wrow = &WhT[mi * WHT_STRIDE + g * 32 + pass * 16];
#pragma unroll
      for (int ffp = 0; ffp < 4; ++ffp) {
        float4 w = *(const float4*)&wrow[ffp * 4];  // wave-uniform broadcast
        G0r[2 * ffp + 0] = fmaf(w.x, hb.x, G0r[2 * ffp + 0]);
        G0i[2 * ffp + 0] = fmaf(w.x, hb.y, G0i[2 * ffp + 0]);
        G1r[2 * ffp + 0] = fmaf(w.y, hb.x, G1r[2 * ffp + 0]);
        G1i[2 * ffp + 0] = fmaf(w.y, hb.y, G1i[2 * ffp + 0]);
        G0r[2 * ffp + 1] = fmaf(w.z, hb.x, G0r[2 * ffp + 1]);
        G0i[2 * ffp + 1] = fmaf(w.z, hb.y, G0i[2 * ffp + 1]);
        G1r[2 * ffp + 1] = fmaf(w.w, hb.x, G1r[2 * ffp + 1]);
        G1i[2 * ffp + 1] = fmaf(w.w, hb.y, G1i[2 * ffp + 1]);
      }
      hb = hn;
    }

#pragma unroll
    for (int ff = 0; ff < 8; ++ff) {
      if (ff < 7) {
#pragma unroll
        for (int b = 0; b < 8; ++b)
          un[b] = kok ? fu2[((size_t)(b * NFEAT + fbase + ff + 1)) * kb + k]
                      : make_float2(0.f, 0.f);
      }
      float gr0 = G0r[ff], gi0 = G0i[ff], gr1 = G1r[ff], gi1 = G1i[ff];
#pragma unroll
      for (int b = 0; b < 8; ++b) {
        float2 u = ub[b];
        zr[0][b] = fmaf(u.x, gr0, fmaf(-u.y, gi0, zr[0][b]));
        zi[0][b] = fmaf(u.x, gi0, fmaf( u.y, gr0, zi[0][b]));
        zr[1][b] = fmaf(u.x, gr1, fmaf(-u.y, gi1, zr[1][b]));
        zi[1][b] = fmaf(u.x, gi1, fmaf( u.y, gr1, zi[1][b]));
      }
#pragma unroll
      for (int b = 0; b < 8; ++b) ub[b] = un[b];
    }
  }
  __syncthreads();   // WhT dead; red overlays it
#pragma unroll
  for (int ol = 0; ol < 2; ++ol)
#pragma unroll
    for (int b = 0; b < 8; ++b) {
      red[g][tk][(ol * 8 + b) * 2 + 0] = zr[ol][b];
      red[g][tk][(ol * 8 + b) * 2 + 1] = zi[ol][b];
    }
  __syncthreads();
  if (g == 0 && kok) {
    float2* Z2 = (float2*)Zc;
#pragma unroll
    for (int ol = 0; ol < 2; ++ol)
#pragma unroll
      for (int b = 0; b < 8; ++b) {
        int i0 = (ol * 8 + b) * 2;
        float sr = red[0][tk][i0]     + red[1][tk][i0]
                 + red[2][tk][i0]     + red[3][tk][i0];
        float si = red[0][tk][i0 + 1] + red[1][tk][i0 + 1]
                 + red[2][tk][i0 + 1] + red[3][tk][i0 + 1];
        Z2[((size_t)b * och + ol0 + ol) * KBINS + k] = make_float2(sr, si);
      }
  }
}

// ---------------------------------------------------------------------------
// k4h: HALF-SIZE irfft; runtime och indexing. 1 block per (b, ol).
// ---------------------------------------------------------------------------
__global__ __launch_bounds__(256) void k4h(
    const float* __restrict__ Zc, const float2* __restrict__ tw,
    float* __restrict__ dout, int ob0, int och) {
  __shared__ float XR[HF_LDS], XI[HF_LDS];
  __shared__ float2 TWS[2048];
  const int tid = threadIdx.x;
  const int b = blockIdx.x / och, ol = blockIdx.x % och;
  const int o = ob0 + ol;
  const float2* Z2 = (const float2*)Zc + ((size_t)b * och + ol) * KBINS;
  for (int i = tid; i < 2048; i += 256) TWS[i] = tw[i];
  __syncthreads();
  for (int k = tid; k < 2048; k += 256) {
    float2 Xk = Z2[k];
    float2 Xm = Z2[2048 - k];
    float sr = Xk.x + Xm.x,  si = Xk.y - Xm.y;
    float dr = Xk.x - Xm.x,  di = Xk.y + Xm.y;
    float2 w = TWS[k];
    float tx = w.x, ty = -w.y;
    float cr = sr - (tx * di + ty * dr);
    float ci = si + (tx * dr - ty * di);
    int r = __brev((unsigned)k) >> 21;
    XR[FIDX(r)] = cr; XI[FIDX(r)] = ci;
  }
  __syncthreads();
  fft2048_core(XR, XI, TWS, true);
  const float inv = 1.0f / (float)NFFT;
  float2* drow = (float2*)(dout + ((size_t)b * NHID + o) * NSEQ);
  for (int n = tid; n < 1024; n += 256) {
    int idx = FIDX(n);
    float2 old = drow[n];
    drow[n] = make_float2(old.x + XR[idx] * inv, old.y + XI[idx] * inv);
  }
}

// ---------------------------------------------------------------------------
extern "C" void kernel_launch(void* const* d_in, const int* in_sizes, int n_in,
                              void* d_out, int out_size, void* d_ws, size_t ws_size,
                              hipStream_t stream) {
  const float* x   = (const float*)d_in[0];
  const float* Wuw = (const float*)d_in[1];
  const float* Wub = (const float*)d_in[2];
  const float* Whw = (const float*)d_in[3];
  const float* Whb = (const float*)d_in[4];
  // d_in[5] (fft_H) intentionally UNUSED: recomputed on-device in fp64.
  float* out = (float*)d_out;
  float* ws  = (float*)d_ws;

  // ---- runtime o-chunk selection from ws_size (never exceed it) ----
  int och = 256;
  while (och > 32) {
    size_t need = ((size_t)FIXED_F + (size_t)och * 32784u) * 4u;
    if (need <= ws_size) break;
    och >>= 1;
  }
  const int noch = 256 / och;
  const int nopair = och / 2;
  const size_t z_f = (size_t)och * 32784u;

  float* fftu = ws;                       // FFTU_SZ
  float* uz   = ws + FFTU_SZ;             // Z slot (>= ubuf & f64 scratch)
  float* fHd  = uz + z_f;
  float2* tw  = (float2*)(fHd + FHD_SZ);
  float* Hbuf = (float*)tw + TW_SZ;
  double* D   = (double*)uz;

  k0_tw<<<8, 256, 0, stream>>>(tw);

  // --- kA chain: expm + power tables ---
  kinit<<<17, 256, 0, stream>>>(D);
  {
    double* t0 = D + DTT0;
    double* t1 = D + DTT1;
    for (int k = 1; k <= 8; ++k) {
      kmm65<<<17, 256, 0, stream>>>(t0, D + DMM, t1, D + DEE0, (double)k);
      double* tmp = t0; t0 = t1; t1 = tmp;
    }
  }
  kmm65<<<17, 256, 0, stream>>>(D + DEE0, D + DEE0, D + DEE1, (double*)nullptr, 1.0);
  kmm65<<<17, 256, 0, stream>>>(D + DEE1, D + DEE1, D + DEE0, (double*)nullptr, 1.0);
  kext<<<17, 256, 0, stream>>>(D + DEE0, D);
  for (int m = 1; m <= 5; ++m)
    kmm64<<<16, 256, 0, stream>>>(D + DPW + (m - 1) * 4096,
                                  D + DPW + (m - 1) * 4096,
                                  D + DPW + m * 4096);
  kmm64<<<16, 256, 0, stream>>>(D + DPW + 5 * 4096, D + DPW + 5 * 4096,
                                D + DMK2 + 4096);
  for (int m = 0; m <= 5; ++m)
    kwlev<<<1, 256, 0, stream>>>(D + DPW + m * 4096, D + DWV, 1 << m);
  for (int m = 1; m <= 4; ++m) {
    int b0 = 1 << m;
    kmm64<<<16, 256, 0, stream>>>(D + DMK2 + (size_t)(b0 / 2) * 4096,
                                  D + DMK2 + (size_t)(b0 / 2) * 4096,
                                  D + DMK2 + (size_t)b0 * 4096);
    int cnt = b0 - 1;
    kmk<<<dim3(16, cnt), 256, 0, stream>>>(D + DMK2 + (size_t)b0 * 4096,
                                           D + DMK2 + 4096,
                                           D + DMK2 + (size_t)(b0 + 1) * 4096);
  }

  kB_cols<<<32, 256, 0, stream>>>(D, Hbuf);
  kC_fft<<<NMEM, 256, 0, stream>>>(Hbuf, tw, fHd);
  k1t<<<dim3(NSEQ / 128, NOUTCH / 64, NB), 256, 0, stream>>>(x, Wuw, Wub, Whb, out, uz);
  k2h<<<NB * NFEAT, 256, 0, stream>>>(uz, tw, fftu);
  const int nwg3 = 8 * nopair * 5;        // XCD swizzle: 5 kt-groups of 8
  for (int oc = 0; oc < noch; ++oc) {
    int ob0 = oc * och;
    k3m<<<nwg3, 256, 0, stream>>>(Whw, fHd, fftu, uz, ob0, och, nopair);
    k4h<<<NB * och, 256, 0, stream>>>(uz, tw, out, ob0, och);
  }
}

// Round 31
// 599.957 us; speedup vs baseline: 1.0554x; 1.0554x over previous
//
#include <hip/hip_runtime.h>
#include <hip/hip_bf16.h>
#include <math.h>

// Problem constants
#define NB 8
#define NIN 256
#define NHID 256
#define NMEM 64
#define NSEQ 2048
#define NFEAT 64
#define NOUTCH 320        // NFEAT + NHID
#define NFFT 4096
#define KBINS 2049        // NSEQ + 1

// ws layout (float offsets) — Z slot sized at RUNTIME from ws_size.
// order: FFTU | Z(och) | FHD | TW | HBUF ; f64 scratch & ubuf overlay Z.
#define FFTU_SZ (NB * NFEAT * KBINS * 2)               // 2,098,176 (8.4 MB)
#define FHD_SZ (NMEM * KBINS * 2)                      // 262,272 (1.05 MB)
#define TW_SZ (2048 * 2)                               // 16 KB
#define HBUF_SZ (NMEM * NSEQ)                          // 131,072 (0.52 MB)
#define FIXED_F (FFTU_SZ + FHD_SZ + TW_SZ + HBUF_SZ)   // 2,495,616 floats

// f64 scratch layout (doubles, based at Z slot; dead before ubuf is written)
#define DMM   0                      // 65x65 scaled blk
#define DTT0  4225                   // Taylor T ping
#define DTT1  8450                   // Taylor T pong
#define DEE0  12675                  // E ping
#define DEE1  16900                  // E pong
#define DPW   21125                  // pw[0..5] = Ad^(2^m), 6*4096
#define DWV   (DPW + 6 * 4096)       // W[r][j] = (Ad^r Bd)[j], 64x64
#define DMK2  (DWV + 4096)           // Mk[k] = (Ad^64)^k, 32*4096

// padded LDS index for FFT arrays (breaks power-of-2 stride bank conflicts)
#define FIDX(i) ((i) + ((i) >> 5) + ((i) >> 10))
#define FFT_LDS 4240
#define HF_LDS 2120

// ---------------------------------------------------------------------------
// shared 4096-pt radix-2 DIT core (data already bit-reversed into XR/XI)
// ---------------------------------------------------------------------------
__device__ __forceinline__ void fft4096_core(float* XR, float* XI,
                                             const float2* TWS, bool inverse) {
#pragma unroll 1
  for (int s = 1; s <= 12; ++s) {
    int half = 1 << (s - 1);
    int shift = 12 - s;
#pragma unroll
    for (int q = 0; q < 8; ++q) {
      int bf = threadIdx.x + q * 256;
      int j = bf & (half - 1);
      int base = ((bf >> (s - 1)) << s) + j;
      float2 w = TWS[j << shift];
      float wr = w.x, wi = inverse ? -w.y : w.y;
      int i0 = FIDX(base), i1 = FIDX(base + half);
      float ar = XR[i0], ai = XI[i0];
      float br = XR[i1], bi = XI[i1];
      float tr = wr * br - wi * bi, ti = wr * bi + wi * br;
      XR[i0] = ar + tr; XI[i0] = ai + ti;
      XR[i1] = ar - tr; XI[i1] = ai - ti;
    }
    __syncthreads();
  }
}

// 2048-pt core: same table, twiddle index j<<(12-s), s=1..11; 4 bf/thread.
__device__ __forceinline__ void fft2048_core(float* XR, float* XI,
                                             const float2* TWS, bool inverse) {
#pragma unroll 1
  for (int s = 1; s <= 11; ++s) {
    int half = 1 << (s - 1);
    int shift = 12 - s;
#pragma unroll
    for (int q = 0; q < 4; ++q) {
      int bf = threadIdx.x + q * 256;
      int j = bf & (half - 1);
      int base = ((bf >> (s - 1)) << s) + j;
      float2 w = TWS[j << shift];
      float wr = w.x, wi = inverse ? -w.y : w.y;
      int i0 = FIDX(base), i1 = FIDX(base + half);
      float ar = XR[i0], ai = XI[i0];
      float br = XR[i1], bi = XI[i1];
      float tr = wr * br - wi * bi, ti = wr * bi + wi * br;
      XR[i0] = ar + tr; XI[i0] = ai + ti;
      XR[i1] = ar - tr; XI[i1] = ai - ti;
    }
    __syncthreads();
  }
}

// ---------------------------------------------------------------------------
// k0: tw[m] = exp(-2*pi*i*m/4096), m in [0,2048), double precision.
// ---------------------------------------------------------------------------
__global__ void k0_tw(float2* __restrict__ tw) {
  int m = blockIdx.x * 256 + threadIdx.x;
  if (m < 2048) {
    double ang = -2.0 * 3.14159265358979323846 * (double)m / 4096.0;
    tw[m] = make_float2((float)cos(ang), (float)sin(ang));
  }
}

// ---------------------------------------------------------------------------
// kA chain: expm + power tables (Taylor 8 terms; s=2, scale=0.25 hardcoded).
// (launch-chain form: 17-block parallel matmuls)
// ---------------------------------------------------------------------------
__global__ __launch_bounds__(256) void kinit(double* __restrict__ D) {
  int e = blockIdx.x * 256 + threadIdx.x;
  if (e < 4225) {
    int i = e / 65, j = e % 65;
    double val = 0.0;
    if (i < 64) {
      double R = (2.0 * i + 1.0) / 2048.0;
      if (j < 64) val = R * ((i < j) ? -1.0 : (((i - j) & 1) ? 1.0 : -1.0));
      else        val = R * ((i & 1) ? -1.0 : 1.0);   // Bc = R*(-1)^i
    }
    D[DMM + e] = 0.25 * val;
    double id = (i == j) ? 1.0 : 0.0;
    D[DTT0 + e] = id; D[DEE0 + e] = id;
  }
}
__global__ __launch_bounds__(256) void kmm65(const double* __restrict__ A,
                                             const double* __restrict__ B,
                                             double* __restrict__ C,
                                             double* __restrict__ E, double kd) {
  int e = blockIdx.x * 256 + threadIdx.x;
  if (e >= 4225) return;
  int i = e / 65, j = e % 65;
  const double* ar = A + i * 65;
  double dot = 0.0;
  for (int l = 0; l < 65; ++l) dot += ar[l] * B[l * 65 + j];
  dot /= kd;
  C[e] = dot;
  if (E) E[e] += dot;
}
__global__ __launch_bounds__(256) void kext(const double* __restrict__ E,
                                            double* __restrict__ D) {
  int e = blockIdx.x * 256 + threadIdx.x;
  if (e < 4096) {
    int i = e >> 6, j = e & 63;
    D[DPW + e] = (double)(float)E[i * 65 + j];
    D[DMK2 + e] = (i == j) ? 1.0 : 0.0;
  } else if (e < 4160) {
    int j = e - 4096;
    D[DWV + j] = (double)(float)E[j * 65 + 64];
  }
}
__global__ __launch_bounds__(256) void kmm64(const double* __restrict__ A,
                                             const double* __restrict__ B,
                                             double* __restrict__ C) {
  int e = blockIdx.x * 256 + threadIdx.x;
  int i = e >> 6, j = e & 63;
  double dot = 0.0;
  for (int l = 0; l < 64; ++l) dot += A[i * 64 + l] * B[l * 64 + j];
  C[e] = dot;
}
__global__ __launch_bounds__(256) void kwlev(const double* __restrict__ P,
                                             double* __restrict__ W, int b0) {
  int tot = 64 * b0;
  for (int e = threadIdx.x; e < tot; e += 256) {
    int t = e >> 6, i = e & 63;
    double dot = 0.0;
    for (int l = 0; l < 64; ++l) dot += P[i * 64 + l] * W[t * 64 + l];
    W[(size_t)(b0 + t) * 64 + i] = dot;
  }
}
__global__ __launch_bounds__(256) void kmk(const double* __restrict__ Q,
                                           const double* __restrict__ Src,
                                           double* __restrict__ Out) {
  int t = blockIdx.y;
  int e = blockIdx.x * 256 + threadIdx.x;
  int i = e >> 6, j = e & 63;
  const double* B = Src + (size_t)t * 4096;
  double dot = 0.0;
  for (int l = 0; l < 64; ++l) dot += Q[i * 64 + l] * B[l * 64 + j];
  Out[(size_t)t * 4096 + e] = dot;
}

// ---------------------------------------------------------------------------
// kB: parallel impulse response. W transposed in LDS (round-17 conflict fix).
// ---------------------------------------------------------------------------
__global__ __launch_bounds__(256) void kB_cols(const double* __restrict__ D,
                                               float* __restrict__ H) {
  const double* W = D + DWV;
  const double* Mrow = D + DMK2 + (size_t)blockIdx.x * 4096;
  __shared__ double Ms[4096];
  __shared__ double WssT[4096];   // WssT[j*64 + r] = W[r*64 + j]
  const int tid = threadIdx.x;
  for (int e = tid; e < 4096; e += 256) {
    Ms[e] = Mrow[e];
    int r = e >> 6, j = e & 63;
    WssT[j * 64 + r] = W[e];
  }
  __syncthreads();
  const int c0 = blockIdx.x * 64;
  for (int e = tid; e < 4096; e += 256) {
    int i = e >> 6, r = e & 63;
    double dot = 0.0;
#pragma unroll 16
    for (int j = 0; j < 64; ++j) dot += Ms[i * 64 + j] * WssT[j * 64 + r];
    H[(size_t)i * NSEQ + c0 + r] = (float)dot;
  }
}

// ---------------------------------------------------------------------------
// kC: fHd[mi,k] = rfft(H[mi,:], n=4096)[k] via LDS FFT. 1 block/row.
// ---------------------------------------------------------------------------
__global__ __launch_bounds__(256) void kC_fft(const float* __restrict__ H,
                                              const float2* __restrict__ tw,
                                              float* __restrict__ fHd) {
  __shared__ float XR[FFT_LDS], XI[FFT_LDS];
  __shared__ float2 TWS[2048];
  const int tid = threadIdx.x;
  const int mi = blockIdx.x;
  const float* src = H + (size_t)mi * NSEQ;
  for (int i = tid; i < NFFT; i += 256) { XR[FIDX(i)] = 0.f; XI[FIDX(i)] = 0.f; }
  for (int i = tid; i < 2048; i += 256) TWS[i] = tw[i];
  __syncthreads();
  for (int i = tid; i < NSEQ; i += 256) {
    int r = __brev((unsigned)i) >> 20;
    XR[FIDX(r)] = src[i];
  }
  __syncthreads();
  fft4096_core(XR, XI, TWS, false);
  float2* dst = (float2*)fHd + (size_t)mi * KBINS;
  for (int k = tid; k < KBINS; k += 256)
    dst[k] = make_float2(XR[FIDX(k)], XI[FIDX(k)]);
}

// ---------------------------------------------------------------------------
// k1t: tiled GEMM out[b,o,s] = bias + sum_i Wu_w[o,i]*x[b,i,s]
// ---------------------------------------------------------------------------
__global__ __launch_bounds__(256) void k1t(
    const float* __restrict__ x, const float* __restrict__ Wuw,
    const float* __restrict__ Wub, const float* __restrict__ Whb,
    float* __restrict__ dout, float* __restrict__ ubuf) {
  __shared__ float xs[32][128];
  __shared__ float wsh[32][68];
  const int tid = threadIdx.x;
  const int b = blockIdx.z;
  const int o0 = blockIdx.y * 64;
  const int s0 = blockIdx.x * 128;
  const int sx = tid & 15, oy = tid >> 4;
  float acc[4][8];
#pragma unroll
  for (int j = 0; j < 4; ++j)
#pragma unroll
    for (int l = 0; l < 8; ++l) acc[j][l] = 0.f;

  for (int i0 = 0; i0 < 256; i0 += 32) {
#pragma unroll
    for (int e4 = tid; e4 < 1024; e4 += 256) {
      int ii = e4 >> 5, ss4 = (e4 & 31) << 2;
      float4 v = *(const float4*)&x[(size_t)(b * NIN + i0 + ii) * NSEQ + s0 + ss4];
      *(float4*)&xs[ii][ss4] = v;
    }
#pragma unroll
    for (int e4 = tid; e4 < 512; e4 += 256) {
      int oj = e4 >> 3, ii4 = (e4 & 7) << 2;
      float4 v = *(const float4*)&Wuw[(o0 + oj) * NIN + i0 + ii4];
      wsh[ii4][oj] = v.x; wsh[ii4 + 1][oj] = v.y;
      wsh[ii4 + 2][oj] = v.z; wsh[ii4 + 3][oj] = v.w;
    }
    __syncthreads();
#pragma unroll 8
    for (int kk = 0; kk < 32; ++kk) {
      float4 a = *(const float4*)&wsh[kk][oy * 4];
      float4 b0 = *(const float4*)&xs[kk][sx * 4];
      float4 b1 = *(const float4*)&xs[kk][64 + sx * 4];
      float av[4] = {a.x, a.y, a.z, a.w};
      float bv[8] = {b0.x, b0.y, b0.z, b0.w, b1.x, b1.y, b1.z, b1.w};
#pragma unroll
      for (int j = 0; j < 4; ++j)
#pragma unroll
        for (int l = 0; l < 8; ++l) acc[j][l] = fmaf(av[j], bv[l], acc[j][l]);
    }
    __syncthreads();
  }
#pragma unroll
  for (int j = 0; j < 4; ++j) {
    int o = o0 + oy * 4 + j;
    if (o < NHID) {
      float bias = Wub[o] + Whb[o];
      size_t base = ((size_t)b * NHID + o) * NSEQ + s0;
      float4 v0 = make_float4(acc[j][0] + bias, acc[j][1] + bias,
                              acc[j][2] + bias, acc[j][3] + bias);
      float4 v1 = make_float4(acc[j][4] + bias, acc[j][5] + bias,
                              acc[j][6] + bias, acc[j][7] + bias);
      *(float4*)&dout[base + sx * 4] = v0;
      *(float4*)&dout[base + 64 + sx * 4] = v1;
    } else {
      float bias = Wub[o];
      size_t base = ((size_t)b * NFEAT + (o - NHID)) * NSEQ + s0;
      float4 v0 = make_float4(fmaxf(acc[j][0] + bias, 0.f), fmaxf(acc[j][1] + bias, 0.f),
                              fmaxf(acc[j][2] + bias, 0.f), fmaxf(acc[j][3] + bias, 0.f));
      float4 v1 = make_float4(fmaxf(acc[j][4] + bias, 0.f), fmaxf(acc[j][5] + bias, 0.f),
                              fmaxf(acc[j][6] + bias, 0.f), fmaxf(acc[j][7] + bias, 0.f));
      *(float4*)&ubuf[base + sx * 4] = v0;
      *(float4*)&ubuf[base + 64 + sx * 4] = v1;
    }
  }
}

// ---------------------------------------------------------------------------
// k2h: HALF-SIZE forward rfft of u (round-24 proven).
// ---------------------------------------------------------------------------
__global__ __launch_bounds__(256) void k2h(
    const float* __restrict__ ubuf, const float2* __restrict__ tw,
    float* __restrict__ fftu) {
  __shared__ float XR[HF_LDS], XI[HF_LDS];
  __shared__ float2 TWS[2048];
  const int tid = threadIdx.x;
  const int b = blockIdx.x >> 6, f = blockIdx.x & 63;
  const float2* src2 = (const float2*)(ubuf + ((size_t)b * NFEAT + f) * NSEQ);
  for (int i = tid; i < 2048; i += 256) TWS[i] = tw[i];
  for (int n = tid; n < 2048; n += 256) {
    float2 y = (n < 1024) ? src2[n] : make_float2(0.f, 0.f);
    int r = __brev((unsigned)n) >> 21;   // 11-bit reversal
    XR[FIDX(r)] = y.x; XI[FIDX(r)] = y.y;
  }
  __syncthreads();
  fft2048_core(XR, XI, TWS, false);
  float2* dst = (float2*)fftu + ((size_t)b * NFEAT + f) * KBINS;
  for (int k = tid; k <= 2048; k += 256) {
    if (k < 2048) {
      int m = (2048 - k) & 2047;
      float yr = XR[FIDX(k)], yi = XI[FIDX(k)];
      float mr = XR[FIDX(m)], mi = XI[FIDX(m)];
      float ar = 0.5f * (yr + mr), ai = 0.5f * (yi - mi);
      float br = 0.5f * (yi + mi), bi = 0.5f * (mr - yr);
      float2 w = TWS[k];               // e^{-2pik/4096}
      float Xr = ar + w.x * br - w.y * bi;
      float Xi = ai + w.x * bi + w.y * br;
      dst[k] = make_float2(Xr, Xi);
    } else {
      dst[2048] = make_float2(XR[FIDX(0)] - XI[FIDX(0)], 0.f);
    }
  }
}

// ---------------------------------------------------------------------------
// k3p: fused G+Z, mi-outer register-G, two passes of 8 f's, runtime o-chunk
// (round-25: single merged dispatch amortizes the 16-block tail).
// ---------------------------------------------------------------------------
#define WHT_STRIDE 132
#define K3_SMEM (64 * WHT_STRIDE + 64 * 65 * 2)   // 16768 floats = 65.5 KB
__global__ __launch_bounds__(256, 2) void k3p(
    const float* __restrict__ Whw, const float* __restrict__ fHd,
    const float* __restrict__ fftu, float* __restrict__ Zc,
    int ob0, int och, int nopair) {
  const int wgid = blockIdx.x;
  const int cxd = wgid & 7;
  const int sdx = wgid >> 3;
  const int opair = sdx % nopair;
  const int kt = cxd + 8 * (sdx / nopair);
  if (kt >= 33) return;

  __shared__ float smem[K3_SMEM];
  float* WhT = smem;                                   // [64][132]
  float2 (*fHc)[65] = (float2(*)[65])(smem + 64 * WHT_STRIDE);  // [64][65]
  float (*red)[64][33] = (float(*)[64][33])smem;       // overlay, post-loop
  const int tid = threadIdx.x;
  const int ol0 = opair * 2;
  const int o0 = ob0 + ol0;
  const int k0 = kt * 64;

  for (int e4 = tid; e4 < 2048; e4 += 256) {
    int ol = e4 >> 10;
    int idx4 = e4 & 1023;
    int f = idx4 >> 4, mi4 = idx4 & 15;
    float4 v = *(const float4*)&Whw[(size_t)(o0 + ol) * 4096 + f * 64 + mi4 * 4];
    WhT[(mi4 * 4 + 0) * WHT_STRIDE + f * 2 + ol] = v.x;
    WhT[(mi4 * 4 + 1) * WHT_STRIDE + f * 2 + ol] = v.y;
    WhT[(mi4 * 4 + 2) * WHT_STRIDE + f * 2 + ol] = v.z;
    WhT[(mi4 * 4 + 3) * WHT_STRIDE + f * 2 + ol] = v.w;
  }
  for (int e = tid; e < 4096; e += 256) {
    int mi = e >> 6, kk = e & 63;
    int k = k0 + kk;
    float2 v = make_float2(0.f, 0.f);
    if (k < KBINS) v = ((const float2*)fHd)[(size_t)mi * KBINS + k];
    fHc[mi][kk] = v;
  }
  __syncthreads();

  const int tk = tid & 63, g = tid >> 6;
  const int k = k0 + tk;
  const bool kok = (k < KBINS);
  const float2* fu2 = (const float2*)fftu;
  const size_t kb = (size_t)KBINS;

  float zr[2][8], zi[2][8];
#pragma unroll
  for (int ol = 0; ol < 2; ++ol)
#pragma unroll
    for (int b = 0; b < 8; ++b) { zr[ol][b] = 0.f; zi[ol][b] = 0.f; }

#pragma unroll 1
  for (int pass = 0; pass < 2; ++pass) {
    const int fbase = g * 16 + pass * 8;
    float2 ub[8], un[8];
#pragma unroll
    for (int b = 0; b < 8; ++b)
      ub[b] = kok ? fu2[((size_t)(b * NFEAT + fbase)) * kb + k]
                  : make_float2(0.f, 0.f);

    float G0r[8], G0i[8], G1r[8], G1i[8];
#pragma unroll
    for (int ff = 0; ff < 8; ++ff) { G0r[ff] = 0.f; G0i[ff] = 0.f;
                                     G1r[ff] = 0.f; G1i[ff] = 0.f; }

#pragma unroll 2
    for (int mi = 0; mi < 64; ++mi) {
      float2 h = fHc[mi][tk];
      const float* wrow = &WhT[mi * WHT_STRIDE + g * 32 + pass * 16];
#pragma unroll
      for (int ffp = 0; ffp < 4; ++ffp) {
        float4 w = *(const float4*)&wrow[ffp * 4];  // wave-uniform broadcast
        G0r[2 * ffp + 0] = fmaf(w.x, h.x, G0r[2 * ffp + 0]);
        G0i[2 * ffp + 0] = fmaf(w.x, h.y, G0i[2 * ffp + 0]);
        G1r[2 * ffp + 0] = fmaf(w.y, h.x, G1r[2 * ffp + 0]);
        G1i[2 * ffp + 0] = fmaf(w.y, h.y, G1i[2 * ffp + 0]);
        G0r[2 * ffp + 1] = fmaf(w.z, h.x, G0r[2 * ffp + 1]);
        G0i[2 * ffp + 1] = fmaf(w.z, h.y, G0i[2 * ffp + 1]);
        G1r[2 * ffp + 1] = fmaf(w.w, h.x, G1r[2 * ffp + 1]);
        G1i[2 * ffp + 1] = fmaf(w.w, h.y, G1i[2 * ffp + 1]);
      }
    }

#pragma unroll
    for (int ff = 0; ff < 8; ++ff) {
      if (ff < 7) {
#pragma unroll
        for (int b = 0; b < 8; ++b)
          un[b] = kok ? fu2[((size_t)(b * NFEAT + fbase + ff + 1)) * kb + k]
                      : make_float2(0.f, 0.f);
      }
      float gr0 = G0r[ff], gi0 = G0i[ff], gr1 = G1r[ff], gi1 = G1i[ff];
#pragma unroll
      for (int b = 0; b < 8; ++b) {
        float2 u = ub[b];
        zr[0][b] = fmaf(u.x, gr0, fmaf(-u.y, gi0, zr[0][b]));
        zi[0][b] = fmaf(u.x, gi0, fmaf( u.y, gr0, zi[0][b]));
        zr[1][b] = fmaf(u.x, gr1, fmaf(-u.y, gi1, zr[1][b]));
        zi[1][b] = fmaf(u.x, gi1, fmaf( u.y, gr1, zi[1][b]));
      }
#pragma unroll
      for (int b = 0; b < 8; ++b) ub[b] = un[b];
    }
  }
  __syncthreads();   // WhT/fHc dead; red overlays them
#pragma unroll
  for (int ol = 0; ol < 2; ++ol)
#pragma unroll
    for (int b = 0; b < 8; ++b) {
      red[g][tk][(ol * 8 + b) * 2 + 0] = zr[ol][b];
      red[g][tk][(ol * 8 + b) * 2 + 1] = zi[ol][b];
    }
  __syncthreads();
  if (g == 0 && kok) {
    float2* Z2 = (float2*)Zc;
#pragma unroll
    for (int ol = 0; ol < 2; ++ol)
#pragma unroll
      for (int b = 0; b < 8; ++b) {
        int i0 = (ol * 8 + b) * 2;
        float sr = red[0][tk][i0]     + red[1][tk][i0]
                 + red[2][tk][i0]     + red[3][tk][i0];
        float si = red[0][tk][i0 + 1] + red[1][tk][i0 + 1]
                 + red[2][tk][i0 + 1] + red[3][tk][i0 + 1];
        Z2[((size_t)b * och + ol0 + ol) * KBINS + k] = make_float2(sr, si);
      }
  }
}

// ---------------------------------------------------------------------------
// k4h: HALF-SIZE irfft; runtime och indexing. 1 block per (b, ol).
// ---------------------------------------------------------------------------
__global__ __launch_bounds__(256) void k4h(
    const float* __restrict__ Zc, const float2* __restrict__ tw,
    float* __restrict__ dout, int ob0, int och) {
  __shared__ float XR[HF_LDS], XI[HF_LDS];
  __shared__ float2 TWS[2048];
  const int tid = threadIdx.x;
  const int b = blockIdx.x / och, ol = blockIdx.x % och;
  const int o = ob0 + ol;
  const float2* Z2 = (const float2*)Zc + ((size_t)b * och + ol) * KBINS;
  for (int i = tid; i < 2048; i += 256) TWS[i] = tw[i];
  __syncthreads();
  for (int k = tid; k < 2048; k += 256) {
    float2 Xk = Z2[k];
    float2 Xm = Z2[2048 - k];
    float sr = Xk.x + Xm.x,  si = Xk.y - Xm.y;
    float dr = Xk.x - Xm.x,  di = Xk.y + Xm.y;
    float2 w = TWS[k];
    float tx = w.x, ty = -w.y;
    float cr = sr - (tx * di + ty * dr);
    float ci = si + (tx * dr - ty * di);
    int r = __brev((unsigned)k) >> 21;
    XR[FIDX(r)] = cr; XI[FIDX(r)] = ci;
  }
  __syncthreads();
  fft2048_core(XR, XI, TWS, true);
  const float inv = 1.0f / (float)NFFT;
  float2* drow = (float2*)(dout + ((size_t)b * NHID + o) * NSEQ);
  for (int n = tid; n < 1024; n += 256) {
    int idx = FIDX(n);
    float2 old = drow[n];
    drow[n] = make_float2(old.x + XR[idx] * inv, old.y + XI[idx] * inv);
  }
}

// ---------------------------------------------------------------------------
extern "C" void kernel_launch(void* const* d_in, const int* in_sizes, int n_in,
                              void* d_out, int out_size, void* d_ws, size_t ws_size,
                              hipStream_t stream) {
  const float* x   = (const float*)d_in[0];
  const float* Wuw = (const float*)d_in[1];
  const float* Wub = (const float*)d_in[2];
  const float* Whw = (const float*)d_in[3];
  const float* Whb = (const float*)d_in[4];
  // d_in[5] (fft_H) intentionally UNUSED: recomputed on-device in fp64.
  float* out = (float*)d_out;
  float* ws  = (float*)d_ws;

  // ---- runtime o-chunk selection from ws_size (never exceed it) ----
  int och = 256;
  while (och > 32) {
    size_t need = ((size_t)FIXED_F + (size_t)och * 32784u) * 4u;
    if (need <= ws_size) break;
    och >>= 1;
  }
  const int noch = 256 / och;
  const int nopair = och / 2;
  const size_t z_f = (size_t)och * 32784u;

  float* fftu = ws;                       // FFTU_SZ
  float* uz   = ws + FFTU_SZ;             // Z slot (>= ubuf & f64 scratch)
  float* fHd  = uz + z_f;
  float2* tw  = (float2*)(fHd + FHD_SZ);
  float* Hbuf = (float*)tw + TW_SZ;
  double* D   = (double*)uz;

  k0_tw<<<8, 256, 0, stream>>>(tw);

  // --- kA chain: expm + power tables ---
  kinit<<<17, 256, 0, stream>>>(D);
  {
    double* t0 = D + DTT0;
    double* t1 = D + DTT1;
    for (int k = 1; k <= 8; ++k) {
      kmm65<<<17, 256, 0, stream>>>(t0, D + DMM, t1, D + DEE0, (double)k);
      double* tmp = t0; t0 = t1; t1 = tmp;
    }
  }
  kmm65<<<17, 256, 0, stream>>>(D + DEE0, D + DEE0, D + DEE1, (double*)nullptr, 1.0);
  kmm65<<<17, 256, 0, stream>>>(D + DEE1, D + DEE1, D + DEE0, (double*)nullptr, 1.0);
  kext<<<17, 256, 0, stream>>>(D + DEE0, D);
  for (int m = 1; m <= 5; ++m)
    kmm64<<<16, 256, 0, stream>>>(D + DPW + (m - 1) * 4096,
                                  D + DPW + (m - 1) * 4096,
                                  D + DPW + m * 4096);
  kmm64<<<16, 256, 0, stream>>>(D + DPW + 5 * 4096, D + DPW + 5 * 4096,
                                D + DMK2 + 4096);
  for (int m = 0; m <= 5; ++m)
    kwlev<<<1, 256, 0, stream>>>(D + DPW + m * 4096, D + DWV, 1 << m);
  for (int m = 1; m <= 4; ++m) {
    int b0 = 1 << m;
    kmm64<<<16, 256, 0, stream>>>(D + DMK2 + (size_t)(b0 / 2) * 4096,
                                  D + DMK2 + (size_t)(b0 / 2) * 4096,
                                  D + DMK2 + (size_t)b0 * 4096);
    int cnt = b0 - 1;
    kmk<<<dim3(16, cnt), 256, 0, stream>>>(D + DMK2 + (size_t)b0 * 4096,
                                           D + DMK2 + 4096,
                                           D + DMK2 + (size_t)(b0 + 1) * 4096);
  }

  kB_cols<<<32, 256, 0, stream>>>(D, Hbuf);
  kC_fft<<<NMEM, 256, 0, stream>>>(Hbuf, tw, fHd);
  k1t<<<dim3(NSEQ / 128, NOUTCH / 64, NB), 256, 0, stream>>>(x, Wuw, Wub, Whb, out, uz);
  k2h<<<NB * NFEAT, 256, 0, stream>>>(uz, tw, fftu);
  const int nwg3 = 8 * nopair * 5;        // XCD swizzle: 5 kt-groups of 8
  for (int oc = 0; oc < noch; ++oc) {
    int ob0 = oc * och;
    k3p<<<nwg3, 256, 0, stream>>>(Whw, fHd, fftu, uz, ob0, och, nopair);
    k4h<<<NB * och, 256, 0, stream>>>(uz, tw, out, ob0, och);
  }
}